// Round 5
// baseline (171.466 us; speedup 1.0000x reference)
//
#include <hip/hip_runtime.h>

typedef __bf16 bf16;
typedef __bf16 bf16x4v __attribute__((ext_vector_type(4)));
typedef __bf16 bf16x8 __attribute__((ext_vector_type(8)));
typedef float f32x4 __attribute__((ext_vector_type(4)));

#define MFMA16(a, b, c) __builtin_amdgcn_mfma_f32_16x16x32_bf16((a), (b), (c), 0, 0, 0)

#if __has_builtin(__builtin_amdgcn_exp2f)
#define EXP2(x) __builtin_amdgcn_exp2f(x)
#else
#define EXP2(x) exp2f(x)
#endif

#define SEQ 2048
#define DM 1024
#define NH 16

typedef __attribute__((address_space(3))) unsigned int lds_u32;
typedef __attribute__((address_space(1))) const unsigned int glb_u32;

__device__ __forceinline__ void gld16(const bf16* g, bf16* l) {
    __builtin_amdgcn_global_load_lds((glb_u32*)g, (lds_u32*)l, 16, 0, 0);
}

// ---------------------------------------------------------------------------
// fused fp32 -> bf16 convert for all three inputs (one launch)
// ---------------------------------------------------------------------------
__global__ __launch_bounds__(256) void cvt_all(const float* __restrict__ X,
                                               const float* __restrict__ Wq,
                                               const float* __restrict__ Wo,
                                               bf16* __restrict__ Xb,
                                               bf16* __restrict__ Wqb,
                                               bf16* __restrict__ Wob) {
    const int i = blockIdx.x * 256 + threadIdx.x;
    const int N1 = (4 * 1024 * 1024) / 4;
    const int N2 = (3 * 1024 * 1024) / 4;
    const float* s; bf16* d; int off;
    if (i < N1)            { s = X;  d = Xb;  off = i; }
    else if (i < N1 + N2)  { s = Wq; d = Wqb; off = i - N1; }
    else                   { s = Wo; d = Wob; off = i - N1 - N2; }
    const float4 v = ((const float4*)s)[off];
    bf16x4v o;
    o.x = (bf16)v.x; o.y = (bf16)v.y; o.z = (bf16)v.z; o.w = (bf16)v.w;
    ((bf16x4v*)d)[off] = o;
}

// ---------------------------------------------------------------------------
// QKV GEMM, 128x128 tile, BK=64, XOR-swizzled global_load_lds staging.
// 2-phase reorder; swapped-operand MFMA for Q/K -> packed 8B stores;
// V via LDS-transpose epilogue; XCD-bijective block swizzle.
// ---------------------------------------------------------------------------
__global__ __launch_bounds__(256) void gemm_qkv(const bf16* __restrict__ A,
                                                const bf16* __restrict__ B,
                                                bf16* __restrict__ qkbuf,
                                                bf16* __restrict__ vtg) {
    __shared__ bf16 smem[16384];  // As(8192) + Bs(8192); T(8704) reuses
    bf16* As = smem;
    bf16* Bs = smem + 8192;

    const int K = DM, tid = threadIdx.x;
    const int lane = tid & 63, w = tid >> 6;
    const int quad = lane >> 4, l15 = lane & 15;
    const int wm = (w & 1) * 64, wn = (w >> 1) * 64;

    // XCD-aware bijective swizzle: nwg = 24*32 = 768 (divisible by 8)
    const int nbx = gridDim.x;                     // 24
    const int orig = blockIdx.y * nbx + blockIdx.x;
    const int cpx = (nbx * gridDim.y) >> 3;        // 96
    const int swz = (orig & 7) * cpx + (orig >> 3);
    const int rowBase = (swz / nbx) * 128, colBase = (swz % nbx) * 128;
    const bool isV = (colBase >= 2 * DM);

    f32x4 acc[4][4] = {};

    auto stage = [&](int k0) {
#pragma unroll
        for (int i = 0; i < 4; ++i) {
            const int c = i * 256 + tid;
            const int row = c >> 3;
            const int sg = (c & 7) ^ (row & 7);
            gld16(A + (size_t)(rowBase + row) * K + k0 + sg * 8,
                  As + (i * 256 + w * 64) * 8);
            gld16(B + (size_t)(colBase + row) * K + k0 + sg * 8,
                  Bs + (i * 256 + w * 64) * 8);
        }
    };

    stage(0);

    for (int k0 = 0; k0 < K; k0 += 64) {
        __syncthreads();   // drain: tile k resident (overlapped w/ prev compute)

        bf16x8 af[2][4], bfr[2][4];
#pragma unroll
        for (int ks = 0; ks < 2; ++ks)
#pragma unroll
            for (int i = 0; i < 4; ++i) {
                const int ra = wm + i * 16 + l15;
                af[ks][i]  = *(const bf16x8*)(As + ra * 64 + (((ks * 4 + quad) ^ (ra & 7)) * 8));
                const int rb = wn + i * 16 + l15;
                bfr[ks][i] = *(const bf16x8*)(Bs + rb * 64 + (((ks * 4 + quad) ^ (rb & 7)) * 8));
            }

        __syncthreads();   // frags in regs; buffer free

        if (k0 + 64 < K) stage(k0 + 64);

        if (isV) {
#pragma unroll
            for (int ks = 0; ks < 2; ++ks)
#pragma unroll
                for (int i = 0; i < 4; ++i)
#pragma unroll
                    for (int j = 0; j < 4; ++j)
                        acc[i][j] = MFMA16(af[ks][i], bfr[ks][j], acc[i][j]);
        } else {
            // swapped operands: acc = C^T (rows = W-col n, cols = X-row m)
#pragma unroll
            for (int ks = 0; ks < 2; ++ks)
#pragma unroll
                for (int i = 0; i < 4; ++i)
#pragma unroll
                    for (int j = 0; j < 4; ++j)
                        acc[i][j] = MFMA16(bfr[ks][j], af[ks][i], acc[i][j]);
        }
    }

    if (!isV) {
        // packed 8B stores: row = m = wm+i*16+l15, col = n = wn+j*16+quad*4+r
#pragma unroll
        for (int i = 0; i < 4; ++i)
#pragma unroll
            for (int j = 0; j < 4; ++j) {
                bf16x4v pk;
#pragma unroll
                for (int r = 0; r < 4; ++r) pk[r] = (bf16)acc[i][j][r];
                *(bf16x4v*)(qkbuf + (size_t)(rowBase + wm + i * 16 + l15) * 2048 +
                            colBase + wn + j * 16 + quad * 4) = pk;
            }
    } else {
        bf16* T = smem;                        // 64 x 136
        const int vcolBase = colBase - 2 * DM;
        const int bb = rowBase >> 11;
        const int sBase = rowBase & 2047;
        const int drow0 = tid >> 4, seg = tid & 15;
#pragma unroll
        for (int c = 0; c < 2; ++c) {
            __syncthreads();
            if ((w >> 1) == c) {
#pragma unroll
                for (int i = 0; i < 4; ++i)
#pragma unroll
                    for (int j = 0; j < 4; ++j) {
                        bf16x4v pk;
#pragma unroll
                        for (int r = 0; r < 4; ++r) pk[r] = (bf16)acc[i][j][r];
                        *(bf16x4v*)(T + (j * 16 + l15) * 136 + wm + i * 16 + quad * 4) = pk;
                    }
            }
            __syncthreads();
#pragma unroll
            for (int rr = 0; rr < 4; ++rr) {
                const int drow = rr * 16 + drow0;
                *(bf16x8*)(vtg + (size_t)(bb * DM + vcolBase + c * 64 + drow) * SEQ +
                           sBase + seg * 8) =
                    *(const bf16x8*)(T + drow * 136 + seg * 8);
            }
        }
    }
}

// ---------------------------------------------------------------------------
// Out-proj GEMM, 64x128 tile, BK=64, swizzled staging, fp32 out.
// 2-phase reorder + swapped-operand MFMA -> float4 C stores + XCD swizzle.
// ---------------------------------------------------------------------------
__global__ __launch_bounds__(256) void gemm_out(const bf16* __restrict__ A,
                                                const bf16* __restrict__ B,
                                                float* __restrict__ C) {
    __shared__ bf16 As[64 * 64];
    __shared__ bf16 Bs[128 * 64];

    const int K = DM, N = DM, tid = threadIdx.x;
    const int lane = tid & 63, w = tid >> 6;
    const int quad = lane >> 4, l15 = lane & 15;
    const int wm = (w & 1) * 32, wn = (w >> 1) * 64;

    const int nbx = gridDim.x;                     // 8
    const int orig = blockIdx.y * nbx + blockIdx.x;
    const int cpx = (nbx * gridDim.y) >> 3;        // 64
    const int swz = (orig & 7) * cpx + (orig >> 3);
    const int rowBase = (swz / nbx) * 64, colBase = (swz % nbx) * 128;

    f32x4 acc[2][4] = {};

    auto stage = [&](int k0) {
#pragma unroll
        for (int i = 0; i < 2; ++i) {
            const int c = i * 256 + tid;
            const int row = c >> 3;
            const int sg = (c & 7) ^ (row & 7);
            gld16(A + (size_t)(rowBase + row) * K + k0 + sg * 8,
                  As + (i * 256 + w * 64) * 8);
        }
#pragma unroll
        for (int i = 0; i < 4; ++i) {
            const int c = i * 256 + tid;
            const int row = c >> 3;
            const int sg = (c & 7) ^ (row & 7);
            gld16(B + (size_t)(colBase + row) * K + k0 + sg * 8,
                  Bs + (i * 256 + w * 64) * 8);
        }
    };

    stage(0);

    for (int k0 = 0; k0 < K; k0 += 64) {
        __syncthreads();

        bf16x8 af[2][2], bfr[2][4];
#pragma unroll
        for (int ks = 0; ks < 2; ++ks) {
#pragma unroll
            for (int i = 0; i < 2; ++i) {
                const int ra = wm + i * 16 + l15;
                af[ks][i] = *(const bf16x8*)(As + ra * 64 + (((ks * 4 + quad) ^ (ra & 7)) * 8));
            }
#pragma unroll
            for (int j = 0; j < 4; ++j) {
                const int rb = wn + j * 16 + l15;
                bfr[ks][j] = *(const bf16x8*)(Bs + rb * 64 + (((ks * 4 + quad) ^ (rb & 7)) * 8));
            }
        }

        __syncthreads();

        if (k0 + 64 < K) stage(k0 + 64);

        // swapped operands: acc = C^T
#pragma unroll
        for (int ks = 0; ks < 2; ++ks)
#pragma unroll
            for (int i = 0; i < 2; ++i)
#pragma unroll
                for (int j = 0; j < 4; ++j)
                    acc[i][j] = MFMA16(bfr[ks][j], af[ks][i], acc[i][j]);
    }

    // float4 stores: row = m = wm+i*16+l15, col = n = wn+j*16+quad*4
#pragma unroll
    for (int i = 0; i < 2; ++i)
#pragma unroll
        for (int j = 0; j < 4; ++j)
            *(f32x4*)(C + (size_t)(rowBase + wm + i * 16 + l15) * N +
                      colBase + wn + j * 16 + quad * 4) = acc[i][j];
}

// ---------------------------------------------------------------------------
// Causal flash attention, S^T formulation, no-max exp2 softmax.
// Round-13: de-paired q-groups for 2x wave parallelism. Each block owns 32
// q-rows (one 16-row group per wave), grid.y 32->64 => 4096 waves (occupancy
// cap 25%->44%; LDS 20.5 KB -> 7 blocks/CU). The (lo,hi) balancing is gone:
// 2048 blocks >> resident capacity, the scheduler backfills; heavy blocks
// launch first (qb = 63 - blockIdx.y) to shrink the drain tail. In this
// decomposition every tile is live for both waves (block q-rows >= last tile
// start), so the live-guard disappears. Pipeline, swizzles, MFMA-ones
// row-sum identical to round-12.
// ---------------------------------------------------------------------------
__global__ __launch_bounds__(128) void attn_fwd(const bf16* __restrict__ qk,
                                                const bf16* __restrict__ vtg,
                                                bf16* __restrict__ ao) {
    __shared__ bf16 Ks[64 * 64];        // [key][d], swizzled segs
    __shared__ bf16 Vts[64 * 64];       // [d][key], swizzled segs
    __shared__ bf16 Pb[2][16 * 72];     // [wave][q][key]

    const int tid = threadIdx.x;
    const int lane = tid & 63, w = tid >> 6;   // w in {0,1}
    const int quad = lane >> 4, l15 = lane & 15;
    const int bh = blockIdx.x;
    const int b = bh >> 4, h = bh & 15;
    const int qb = 63 - blockIdx.y;            // heavy blocks first
    const int g = qb * 32 + w * 16;

    const bf16* qkb   = qk + (size_t)b * SEQ * 2048;
    const bf16* kbase = qkb + DM + h * 64;
    const bf16* vb    = vtg + (size_t)bh * 64 * SEQ;

    auto stage = [&](int k0) {
#pragma unroll
        for (int i = 0; i < 4; ++i) {   // 512 chunks each of K,V / 128 thr
            const int c = i * 128 + tid;
            const int row = c >> 3;
            const int sg = (c & 7) ^ (row & 7);
            gld16(kbase + (size_t)(k0 + row) * 2048 + sg * 8,
                  Ks + (i * 128 + w * 64) * 8);
            gld16(vb + (size_t)row * SEQ + k0 + sg * 8,
                  Vts + (i * 128 + w * 64) * 8);
        }
    };

    const int nkt = ((qb * 32 + 31) >> 6) + 1;

    // prologue: stage tile 0 (DMA overlaps the Q-fragment global loads)
    stage(0);

    // Q fragments; fold (1/8)*log2(e) so softmax runs in exp2 domain
    const float SC = 0.125f * 1.44269504f;
    bf16x8 qlo, qhi;
    {
        const bf16* qp = qkb + (size_t)(g + l15) * 2048 + h * 64 + quad * 8;
        bf16x8 a = *(const bf16x8*)qp, c = *(const bf16x8*)(qp + 32);
#pragma unroll
        for (int i = 0; i < 8; ++i) {
            qlo[i] = (bf16)((float)a[i] * SC);
            qhi[i] = (bf16)((float)c[i] * SC);
        }
    }

    bf16x8 onesf;
#pragma unroll
    for (int i = 0; i < 8; ++i) onesf[i] = (bf16)1.0f;

    f32x4 o[4] = {};
    f32x4 ol = {};

    for (int kt = 0; kt < nkt; ++kt) {
        const int k0 = kt * 64;
        __syncthreads();   // vmcnt drain: tile kt resident (overlapped w/ prev compute)

        // consume K and V fragments from LDS into registers
        bf16x8 kf[8], vf[8];
#pragma unroll
        for (int t = 0; t < 4; ++t) {
            const int rk = t * 16 + l15;
            kf[2 * t]     = *(const bf16x8*)(Ks + rk * 64 + ((quad ^ (rk & 7)) * 8));
            kf[2 * t + 1] = *(const bf16x8*)(Ks + rk * 64 + (((4 + quad) ^ (rk & 7)) * 8));
            vf[2 * t]     = *(const bf16x8*)(Vts + rk * 64 + ((quad ^ (rk & 7)) * 8));
            vf[2 * t + 1] = *(const bf16x8*)(Vts + rk * 64 + (((4 + quad) ^ (rk & 7)) * 8));
        }

        __syncthreads();   // all waves done reading Ks/Vts

        // issue next tile's staging NOW — latency hides under compute below
        if (kt + 1 < nkt) stage(k0 + 64);

        f32x4 s[4];
#pragma unroll
        for (int t = 0; t < 4; ++t) {
            f32x4 z = {};
            z = MFMA16(kf[2 * t], qlo, z);
            z = MFMA16(kf[2 * t + 1], qhi, z);
            s[t] = z;
        }

        // softmax without running max: p = exp2(s); row-sum via ones-MFMA
        if (k0 + 63 > g) {  // diagonal: causal mask
#pragma unroll
            for (int t = 0; t < 4; ++t)
#pragma unroll
                for (int r = 0; r < 4; ++r)
                    if (k0 + t * 16 + quad * 4 + r > g + l15) s[t][r] = -1e30f;
        }
        bf16* P = &Pb[w][0];
#pragma unroll
        for (int t = 0; t < 4; ++t) {
            bf16x4v pb4;
#pragma unroll
            for (int r = 0; r < 4; ++r) pb4[r] = (bf16)EXP2(s[t][r]);
            *(bf16x4v*)(P + l15 * 72 + t * 16 + quad * 4) = pb4;
        }

        asm volatile("s_waitcnt lgkmcnt(0)" ::: "memory");

        bf16x8 pa = *(const bf16x8*)(P + l15 * 72 + quad * 8);
        bf16x8 pb = *(const bf16x8*)(P + l15 * 72 + 32 + quad * 8);

#pragma unroll
        for (int dt = 0; dt < 4; ++dt) {
            o[dt] = MFMA16(vf[2 * dt], pa, o[dt]);
            o[dt] = MFMA16(vf[2 * dt + 1], pb, o[dt]);
        }
        // row-sum of P via ones-fragment: every lane gets complete l(q=l15)
        ol = MFMA16(onesf, pa, ol);
        ol = MFMA16(onesf, pb, ol);
    }

    const float inv = 1.f / ol[0];
    bf16* a = ao + (size_t)(b * SEQ + g + l15) * DM + h * 64;
#pragma unroll
    for (int dt = 0; dt < 4; ++dt) {
        bf16x4v v;
#pragma unroll
        for (int r = 0; r < 4; ++r) v[r] = (bf16)(o[dt][r] * inv);
        *(bf16x4v*)(a + dt * 16 + quad * 4) = v;
    }
}

// ---------------------------------------------------------------------------
extern "C" void kernel_launch(void* const* d_in, const int* in_sizes, int n_in,
                              void* d_out, int out_size, void* d_ws, size_t ws_size,
                              hipStream_t stream) {
    const float* X    = (const float*)d_in[0];
    const float* Wqkv = (const float*)d_in[1];
    const float* Wout = (const float*)d_in[2];
    float* out = (float*)d_out;

    const int M = 2 * SEQ;  // 4096
    const size_t nX    = (size_t)M * DM;
    const size_t nWqkv = (size_t)3 * DM * DM;
    const size_t nWout = (size_t)DM * DM;
    const size_t nQK   = (size_t)M * 2 * DM;
    const size_t nVT   = (size_t)2 * DM * SEQ;
    const size_t nAO   = (size_t)M * DM;

    if (ws_size < (nX + nWqkv + nWout + nQK + nVT + nAO) * sizeof(bf16)) return;

    bf16* Xb    = (bf16*)d_ws;
    bf16* Wqkvb = Xb + nX;
    bf16* Woutb = Wqkvb + nWqkv;
    bf16* qkbuf = Woutb + nWout;
    bf16* vtg   = qkbuf + nQK;
    bf16* ao    = vtg + nVT;

    const int nCvt4 = (int)((nX + nWqkv + nWout) / 4);
    cvt_all<<<dim3(nCvt4 / 256), 256, 0, stream>>>(X, Wqkv, Wout, Xb, Wqkvb, Woutb);

    gemm_qkv<<<dim3(3 * DM / 128, M / 128), 256, 0, stream>>>(Xb, Wqkvb, qkbuf, vtg);
    attn_fwd<<<dim3(2 * NH, SEQ / 32), 128, 0, stream>>>(qkbuf, vtg, ao);
    gemm_out<<<dim3(DM / 128, M / 64), 256, 0, stream>>>(ao, Woutb, out);
}

// Round 6
// 159.532 us; speedup vs baseline: 1.0748x; 1.0748x over previous
//
#include <hip/hip_runtime.h>

typedef __bf16 bf16;
typedef __bf16 bf16x4v __attribute__((ext_vector_type(4)));
typedef __bf16 bf16x8 __attribute__((ext_vector_type(8)));
typedef float f32x4 __attribute__((ext_vector_type(4)));

#define MFMA16(a, b, c) __builtin_amdgcn_mfma_f32_16x16x32_bf16((a), (b), (c), 0, 0, 0)

#if __has_builtin(__builtin_amdgcn_exp2f)
#define EXP2(x) __builtin_amdgcn_exp2f(x)
#else
#define EXP2(x) exp2f(x)
#endif

#define SEQ 2048
#define DM 1024
#define NH 16

typedef __attribute__((address_space(3))) unsigned int lds_u32;
typedef __attribute__((address_space(1))) const unsigned int glb_u32;

__device__ __forceinline__ void gld16(const bf16* g, bf16* l) {
    __builtin_amdgcn_global_load_lds((glb_u32*)g, (lds_u32*)l, 16, 0, 0);
}

// ---------------------------------------------------------------------------
// fused fp32 -> bf16 convert for all three inputs (one launch)
// ---------------------------------------------------------------------------
__global__ __launch_bounds__(256) void cvt_all(const float* __restrict__ X,
                                               const float* __restrict__ Wq,
                                               const float* __restrict__ Wo,
                                               bf16* __restrict__ Xb,
                                               bf16* __restrict__ Wqb,
                                               bf16* __restrict__ Wob) {
    const int i = blockIdx.x * 256 + threadIdx.x;
    const int N1 = (4 * 1024 * 1024) / 4;
    const int N2 = (3 * 1024 * 1024) / 4;
    const float* s; bf16* d; int off;
    if (i < N1)            { s = X;  d = Xb;  off = i; }
    else if (i < N1 + N2)  { s = Wq; d = Wqb; off = i - N1; }
    else                   { s = Wo; d = Wob; off = i - N1 - N2; }
    const float4 v = ((const float4*)s)[off];
    bf16x4v o;
    o.x = (bf16)v.x; o.y = (bf16)v.y; o.z = (bf16)v.z; o.w = (bf16)v.w;
    ((bf16x4v*)d)[off] = o;
}

// ---------------------------------------------------------------------------
// QKV GEMM, 128x128 tile, BK=64, XOR-swizzled global_load_lds staging.
// 2-phase reorder; swapped-operand MFMA for Q/K -> packed 8B stores;
// V via LDS-transpose epilogue; XCD-bijective block swizzle.
// ---------------------------------------------------------------------------
__global__ __launch_bounds__(256) void gemm_qkv(const bf16* __restrict__ A,
                                                const bf16* __restrict__ B,
                                                bf16* __restrict__ qkbuf,
                                                bf16* __restrict__ vtg) {
    __shared__ bf16 smem[16384];  // As(8192) + Bs(8192); T(8704) reuses
    bf16* As = smem;
    bf16* Bs = smem + 8192;

    const int K = DM, tid = threadIdx.x;
    const int lane = tid & 63, w = tid >> 6;
    const int quad = lane >> 4, l15 = lane & 15;
    const int wm = (w & 1) * 64, wn = (w >> 1) * 64;

    // XCD-aware bijective swizzle: nwg = 24*32 = 768 (divisible by 8)
    const int nbx = gridDim.x;                     // 24
    const int orig = blockIdx.y * nbx + blockIdx.x;
    const int cpx = (nbx * gridDim.y) >> 3;        // 96
    const int swz = (orig & 7) * cpx + (orig >> 3);
    const int rowBase = (swz / nbx) * 128, colBase = (swz % nbx) * 128;
    const bool isV = (colBase >= 2 * DM);

    f32x4 acc[4][4] = {};

    auto stage = [&](int k0) {
#pragma unroll
        for (int i = 0; i < 4; ++i) {
            const int c = i * 256 + tid;
            const int row = c >> 3;
            const int sg = (c & 7) ^ (row & 7);
            gld16(A + (size_t)(rowBase + row) * K + k0 + sg * 8,
                  As + (i * 256 + w * 64) * 8);
            gld16(B + (size_t)(colBase + row) * K + k0 + sg * 8,
                  Bs + (i * 256 + w * 64) * 8);
        }
    };

    stage(0);

    for (int k0 = 0; k0 < K; k0 += 64) {
        __syncthreads();   // drain: tile k resident (overlapped w/ prev compute)

        bf16x8 af[2][4], bfr[2][4];
#pragma unroll
        for (int ks = 0; ks < 2; ++ks)
#pragma unroll
            for (int i = 0; i < 4; ++i) {
                const int ra = wm + i * 16 + l15;
                af[ks][i]  = *(const bf16x8*)(As + ra * 64 + (((ks * 4 + quad) ^ (ra & 7)) * 8));
                const int rb = wn + i * 16 + l15;
                bfr[ks][i] = *(const bf16x8*)(Bs + rb * 64 + (((ks * 4 + quad) ^ (rb & 7)) * 8));
            }

        __syncthreads();   // frags in regs; buffer free

        if (k0 + 64 < K) stage(k0 + 64);

        if (isV) {
#pragma unroll
            for (int ks = 0; ks < 2; ++ks)
#pragma unroll
                for (int i = 0; i < 4; ++i)
#pragma unroll
                    for (int j = 0; j < 4; ++j)
                        acc[i][j] = MFMA16(af[ks][i], bfr[ks][j], acc[i][j]);
        } else {
            // swapped operands: acc = C^T (rows = W-col n, cols = X-row m)
#pragma unroll
            for (int ks = 0; ks < 2; ++ks)
#pragma unroll
                for (int i = 0; i < 4; ++i)
#pragma unroll
                    for (int j = 0; j < 4; ++j)
                        acc[i][j] = MFMA16(bfr[ks][j], af[ks][i], acc[i][j]);
        }
    }

    if (!isV) {
        // packed 8B stores: row = m = wm+i*16+l15, col = n = wn+j*16+quad*4+r
#pragma unroll
        for (int i = 0; i < 4; ++i)
#pragma unroll
            for (int j = 0; j < 4; ++j) {
                bf16x4v pk;
#pragma unroll
                for (int r = 0; r < 4; ++r) pk[r] = (bf16)acc[i][j][r];
                *(bf16x4v*)(qkbuf + (size_t)(rowBase + wm + i * 16 + l15) * 2048 +
                            colBase + wn + j * 16 + quad * 4) = pk;
            }
    } else {
        bf16* T = smem;                        // 64 x 136
        const int vcolBase = colBase - 2 * DM;
        const int bb = rowBase >> 11;
        const int sBase = rowBase & 2047;
        const int drow0 = tid >> 4, seg = tid & 15;
#pragma unroll
        for (int c = 0; c < 2; ++c) {
            __syncthreads();
            if ((w >> 1) == c) {
#pragma unroll
                for (int i = 0; i < 4; ++i)
#pragma unroll
                    for (int j = 0; j < 4; ++j) {
                        bf16x4v pk;
#pragma unroll
                        for (int r = 0; r < 4; ++r) pk[r] = (bf16)acc[i][j][r];
                        *(bf16x4v*)(T + (j * 16 + l15) * 136 + wm + i * 16 + quad * 4) = pk;
                    }
            }
            __syncthreads();
#pragma unroll
            for (int rr = 0; rr < 4; ++rr) {
                const int drow = rr * 16 + drow0;
                *(bf16x8*)(vtg + (size_t)(bb * DM + vcolBase + c * 64 + drow) * SEQ +
                           sBase + seg * 8) =
                    *(const bf16x8*)(T + drow * 136 + seg * 8);
            }
        }
    }
}

// ---------------------------------------------------------------------------
// Out-proj GEMM, 64x128 tile, BK=64, swizzled staging, fp32 out.
// 2-phase reorder + swapped-operand MFMA -> float4 C stores + XCD swizzle.
// ---------------------------------------------------------------------------
__global__ __launch_bounds__(256) void gemm_out(const bf16* __restrict__ A,
                                                const bf16* __restrict__ B,
                                                float* __restrict__ C) {
    __shared__ bf16 As[64 * 64];
    __shared__ bf16 Bs[128 * 64];

    const int K = DM, N = DM, tid = threadIdx.x;
    const int lane = tid & 63, w = tid >> 6;
    const int quad = lane >> 4, l15 = lane & 15;
    const int wm = (w & 1) * 32, wn = (w >> 1) * 64;

    const int nbx = gridDim.x;                     // 8
    const int orig = blockIdx.y * nbx + blockIdx.x;
    const int cpx = (nbx * gridDim.y) >> 3;        // 64
    const int swz = (orig & 7) * cpx + (orig >> 3);
    const int rowBase = (swz / nbx) * 64, colBase = (swz % nbx) * 128;

    f32x4 acc[2][4] = {};

    auto stage = [&](int k0) {
#pragma unroll
        for (int i = 0; i < 2; ++i) {
            const int c = i * 256 + tid;
            const int row = c >> 3;
            const int sg = (c & 7) ^ (row & 7);
            gld16(A + (size_t)(rowBase + row) * K + k0 + sg * 8,
                  As + (i * 256 + w * 64) * 8);
        }
#pragma unroll
        for (int i = 0; i < 4; ++i) {
            const int c = i * 256 + tid;
            const int row = c >> 3;
            const int sg = (c & 7) ^ (row & 7);
            gld16(B + (size_t)(colBase + row) * K + k0 + sg * 8,
                  Bs + (i * 256 + w * 64) * 8);
        }
    };

    stage(0);

    for (int k0 = 0; k0 < K; k0 += 64) {
        __syncthreads();

        bf16x8 af[2][2], bfr[2][4];
#pragma unroll
        for (int ks = 0; ks < 2; ++ks) {
#pragma unroll
            for (int i = 0; i < 2; ++i) {
                const int ra = wm + i * 16 + l15;
                af[ks][i] = *(const bf16x8*)(As + ra * 64 + (((ks * 4 + quad) ^ (ra & 7)) * 8));
            }
#pragma unroll
            for (int j = 0; j < 4; ++j) {
                const int rb = wn + j * 16 + l15;
                bfr[ks][j] = *(const bf16x8*)(Bs + rb * 64 + (((ks * 4 + quad) ^ (rb & 7)) * 8));
            }
        }

        __syncthreads();

        if (k0 + 64 < K) stage(k0 + 64);

        // swapped operands: acc = C^T
#pragma unroll
        for (int ks = 0; ks < 2; ++ks)
#pragma unroll
            for (int i = 0; i < 2; ++i)
#pragma unroll
                for (int j = 0; j < 4; ++j)
                    acc[i][j] = MFMA16(bfr[ks][j], af[ks][i], acc[i][j]);
    }

    // float4 stores: row = m = wm+i*16+l15, col = n = wn+j*16+quad*4
#pragma unroll
    for (int i = 0; i < 2; ++i)
#pragma unroll
        for (int j = 0; j < 4; ++j)
            *(f32x4*)(C + (size_t)(rowBase + wm + i * 16 + l15) * N +
                      colBase + wn + j * 16 + quad * 4) = acc[i][j];
}

// ---------------------------------------------------------------------------
// Causal flash attention, S^T formulation, no-max exp2 softmax.
// Round-14: 4-wave blocks sharing one stage. Block = 256 threads covering 64
// contiguous q-rows (one 16-row group per wave); grid (32 bh, 32 qb) = 1024
// blocks x 4 waves = 4096 waves (2x round-12) while block-tile staging count
// stays at round-12's level (~17K tiles, amortized over 4 waves). Residency:
// 4 blocks/CU = 16 waves/CU (occupancy cap 50%). Strided block->CU placement
// spreads qb evenly -> uniform per-CU work; heavy-first launch order (qb =
// 31 - blockIdx.y) shrinks the drain tail. Causal mask only on each block's
// last tile (kt == qb), wave-uniform. Pipeline, swizzles, MFMA-ones row-sum
// identical to round-12/13.
// ---------------------------------------------------------------------------
__global__ __launch_bounds__(256) void attn_fwd(const bf16* __restrict__ qk,
                                                const bf16* __restrict__ vtg,
                                                bf16* __restrict__ ao) {
    __shared__ bf16 Ks[64 * 64];        // [key][d], swizzled segs
    __shared__ bf16 Vts[64 * 64];       // [d][key], swizzled segs
    __shared__ bf16 Pb[4][16 * 72];     // [wave][q][key]

    const int tid = threadIdx.x;
    const int lane = tid & 63, w = tid >> 6;   // w in {0..3}
    const int quad = lane >> 4, l15 = lane & 15;
    const int bh = blockIdx.x;
    const int b = bh >> 4, h = bh & 15;
    const int qb = 31 - blockIdx.y;            // heavy blocks first
    const int g = qb * 64 + w * 16;

    const bf16* qkb   = qk + (size_t)b * SEQ * 2048;
    const bf16* kbase = qkb + DM + h * 64;
    const bf16* vb    = vtg + (size_t)bh * 64 * SEQ;

    auto stage = [&](int k0) {
#pragma unroll
        for (int i = 0; i < 2; ++i) {   // 512 chunks each of K,V / 256 thr
            const int c = i * 256 + tid;
            const int row = c >> 3;
            const int sg = (c & 7) ^ (row & 7);
            gld16(kbase + (size_t)(k0 + row) * 2048 + sg * 8,
                  Ks + (i * 256 + w * 64) * 8);
            gld16(vb + (size_t)row * SEQ + k0 + sg * 8,
                  Vts + (i * 256 + w * 64) * 8);
        }
    };

    const int nkt = qb + 1;

    // prologue: stage tile 0 (DMA overlaps the Q-fragment global loads)
    stage(0);

    // Q fragments; fold (1/8)*log2(e) so softmax runs in exp2 domain
    const float SC = 0.125f * 1.44269504f;
    bf16x8 qlo, qhi;
    {
        const bf16* qp = qkb + (size_t)(g + l15) * 2048 + h * 64 + quad * 8;
        bf16x8 a = *(const bf16x8*)qp, c = *(const bf16x8*)(qp + 32);
#pragma unroll
        for (int i = 0; i < 8; ++i) {
            qlo[i] = (bf16)((float)a[i] * SC);
            qhi[i] = (bf16)((float)c[i] * SC);
        }
    }

    bf16x8 onesf;
#pragma unroll
    for (int i = 0; i < 8; ++i) onesf[i] = (bf16)1.0f;

    f32x4 o[4] = {};
    f32x4 ol = {};

    for (int kt = 0; kt < nkt; ++kt) {
        const int k0 = kt * 64;
        __syncthreads();   // vmcnt drain: tile kt resident (overlapped w/ prev compute)

        // consume K and V fragments from LDS into registers
        bf16x8 kf[8], vf[8];
#pragma unroll
        for (int t = 0; t < 4; ++t) {
            const int rk = t * 16 + l15;
            kf[2 * t]     = *(const bf16x8*)(Ks + rk * 64 + ((quad ^ (rk & 7)) * 8));
            kf[2 * t + 1] = *(const bf16x8*)(Ks + rk * 64 + (((4 + quad) ^ (rk & 7)) * 8));
            vf[2 * t]     = *(const bf16x8*)(Vts + rk * 64 + ((quad ^ (rk & 7)) * 8));
            vf[2 * t + 1] = *(const bf16x8*)(Vts + rk * 64 + (((4 + quad) ^ (rk & 7)) * 8));
        }

        __syncthreads();   // all waves done reading Ks/Vts

        // issue next tile's staging NOW — latency hides under compute below
        if (kt + 1 < nkt) stage(k0 + 64);

        f32x4 s[4];
#pragma unroll
        for (int t = 0; t < 4; ++t) {
            f32x4 z = {};
            z = MFMA16(kf[2 * t], qlo, z);
            z = MFMA16(kf[2 * t + 1], qhi, z);
            s[t] = z;
        }

        // softmax without running max: p = exp2(s); row-sum via ones-MFMA
        if (kt == qb) {  // diagonal tile: causal mask (wave-uniform branch)
#pragma unroll
            for (int t = 0; t < 4; ++t)
#pragma unroll
                for (int r = 0; r < 4; ++r)
                    if (k0 + t * 16 + quad * 4 + r > g + l15) s[t][r] = -1e30f;
        }
        bf16* P = &Pb[w][0];
#pragma unroll
        for (int t = 0; t < 4; ++t) {
            bf16x4v pb4;
#pragma unroll
            for (int r = 0; r < 4; ++r) pb4[r] = (bf16)EXP2(s[t][r]);
            *(bf16x4v*)(P + l15 * 72 + t * 16 + quad * 4) = pb4;
        }

        asm volatile("s_waitcnt lgkmcnt(0)" ::: "memory");

        bf16x8 pa = *(const bf16x8*)(P + l15 * 72 + quad * 8);
        bf16x8 pb = *(const bf16x8*)(P + l15 * 72 + 32 + quad * 8);

#pragma unroll
        for (int dt = 0; dt < 4; ++dt) {
            o[dt] = MFMA16(vf[2 * dt], pa, o[dt]);
            o[dt] = MFMA16(vf[2 * dt + 1], pb, o[dt]);
        }
        // row-sum of P via ones-fragment: every lane gets complete l(q=l15)
        ol = MFMA16(onesf, pa, ol);
        ol = MFMA16(onesf, pb, ol);
    }

    const float inv = 1.f / ol[0];
    bf16* a = ao + (size_t)(b * SEQ + g + l15) * DM + h * 64;
#pragma unroll
    for (int dt = 0; dt < 4; ++dt) {
        bf16x4v v;
#pragma unroll
        for (int r = 0; r < 4; ++r) v[r] = (bf16)(o[dt][r] * inv);
        *(bf16x4v*)(a + dt * 16 + quad * 4) = v;
    }
}

// ---------------------------------------------------------------------------
extern "C" void kernel_launch(void* const* d_in, const int* in_sizes, int n_in,
                              void* d_out, int out_size, void* d_ws, size_t ws_size,
                              hipStream_t stream) {
    const float* X    = (const float*)d_in[0];
    const float* Wqkv = (const float*)d_in[1];
    const float* Wout = (const float*)d_in[2];
    float* out = (float*)d_out;

    const int M = 2 * SEQ;  // 4096
    const size_t nX    = (size_t)M * DM;
    const size_t nWqkv = (size_t)3 * DM * DM;
    const size_t nWout = (size_t)DM * DM;
    const size_t nQK   = (size_t)M * 2 * DM;
    const size_t nVT   = (size_t)2 * DM * SEQ;
    const size_t nAO   = (size_t)M * DM;

    if (ws_size < (nX + nWqkv + nWout + nQK + nVT + nAO) * sizeof(bf16)) return;

    bf16* Xb    = (bf16*)d_ws;
    bf16* Wqkvb = Xb + nX;
    bf16* Woutb = Wqkvb + nWqkv;
    bf16* qkbuf = Woutb + nWout;
    bf16* vtg   = qkbuf + nQK;
    bf16* ao    = vtg + nVT;

    const int nCvt4 = (int)((nX + nWqkv + nWout) / 4);
    cvt_all<<<dim3(nCvt4 / 256), 256, 0, stream>>>(X, Wqkv, Wout, Xb, Wqkvb, Woutb);

    gemm_qkv<<<dim3(3 * DM / 128, M / 128), 256, 0, stream>>>(Xb, Wqkvb, qkbuf, vtg);
    attn_fwd<<<dim3(2 * NH, SEQ / 64), 256, 0, stream>>>(qkbuf, vtg, ao);
    gemm_out<<<dim3(DM / 128, M / 64), 256, 0, stream>>>(ao, Woutb, out);
}